// Round 6
// baseline (682.124 us; speedup 1.0000x reference)
//
#include <hip/hip_runtime.h>
#include <hip/hip_cooperative_groups.h>
#include <math.h>

namespace cg = cooperative_groups;

// Problem constants: D_MODEL=4, D_INNER=8, D_STATE=16, D_CONV=4, DT_RANK=1
// x: (B=4, N=6, H=128, W=128) f32. L = 98304.
#define HWSZ  16384
#define LTOT  98304
#define NB    4
#define TCH   96           // chunk length
#define NCH   1024         // LTOT / TCH
#define GCH   64           // chunks per combine group
#define NGRP  16           // NCH / GCH
#define SD    100          // scan t-stride: %4==0 (b128 align), d-offset 4 banks (2-way max = free)
#define NBL   (NB * LTOT)
#define NTASK (NCH * NB)   // 4096 chunk tasks
#define FTASK (NBL / 128)  // 3072 final tasks

// ---- shared overlay (floats). scan: pre|dt|dxm|Bv|Cv ; corr: yf|sg|xm|Ct|zs|hA
#define O_PRE 0            // 892  (TCH+3)*9 = 891
#define O_DT  892          // 800
#define O_DXM 1692         // 800
#define O_BV  2492         // 1600
#define O_CV  4092         // 1600 -> 5692
#define C_SG  892          // 832  (8*104)
#define C_XM  1724         // 768
#define C_CT  2492         // 1920 (96*20)
#define C_ZS  4412         // 768
#define C_HA  5180         // 256  -> 5436
#define SMEMF 5692         // 22768 B -> 7 blocks/CU by LDS; we request 6

// fast transcendentals: v_exp/v_log/v_rcp based; rel err ~1e-7, budget 2.7e-4
__device__ __forceinline__ float siluf(float x){
  return x * __builtin_amdgcn_rcpf(1.f + __expf(-x));
}
__device__ __forceinline__ float softplusf(float x){
  return fmaxf(x, 0.f) + __logf(1.f + __expf(-fabsf(x)));
}

// 16-lane (row-aligned) sum via DPP butterflies — pure VALU, no DS ops.
__device__ __forceinline__ float red16(float x){
  int v;
  v = __float_as_int(x);
  x += __int_as_float(__builtin_amdgcn_update_dpp(0, v, 0xB1, 0xF, 0xF, true));   // quad_perm xor1
  v = __float_as_int(x);
  x += __int_as_float(__builtin_amdgcn_update_dpp(0, v, 0x4E, 0xF, 0xF, true));   // quad_perm xor2
  v = __float_as_int(x);
  x += __int_as_float(__builtin_amdgcn_update_dpp(0, v, 0x141, 0xF, 0xF, true));  // row_half_mirror
  v = __float_as_int(x);
  x += __int_as_float(__builtin_amdgcn_update_dpp(0, v, 0x140, 0xF, 0xF, true));  // row_mirror
  return x;
}

// floor(sqrt(v)) exact for 0 <= v <= 2^24 via rn + one-step fixup
__device__ __forceinline__ int isqrt_floor(int v){
  int r = __float2int_rn(sqrtf((float)v));
  if (r * r > v) --r;
  else if ((r + 1) * (r + 1) <= v) ++r;
  return r;
}

// perm k=0 (scanA): i = n*HW + r -> spatial n*HW + sp[r]
__device__ __forceinline__ int rho0(int i, const int* __restrict__ sp){
  int n = i >> 14; int r = i & (HWSZ - 1);
  return (n << 14) + sp[r];
}
// perm k=1 (scanB): i = r*6 + n ; tid = (r even ? n : 5-n) -> tid*HW + sp[r]
__device__ __forceinline__ int rho1(int i, const int* __restrict__ sp){
  unsigned ui = (unsigned)i;
  unsigned r = ui / 6u; unsigned n = ui - r * 6u;
  unsigned t = (r & 1u) ? (5u - n) : n;
  return (int)((t << 14) + (unsigned)sp[r]);
}
// k=2 is rho0(L-1-i), k=3 is rho1(L-1-i)

struct Params {
  const float* X;
  const float* dww; const float* dwb;
  const float* ipw;
  const float* c1w; const float* c1b;
  const float* xpw;
  const float* dtpw; const float* dtpb;
  const float* Alog; const float* Dp;
  const float* opw;
  const float* lng; const float* lnb;
  int* sp;
  float* chA; float* chB; float* hpre; float* apre;
  float* GA; float* GB;
  float4* ug4; float* y0g; float* outbuf; float* out;
};

__global__ __launch_bounds__(128, 4)
void k_mega(Params p)
{
  __shared__ __align__(16) float smem[SMEMF];
  cg::grid_group grid = cg::this_grid();
  const int tid = threadIdx.x;
  const int nbk = gridDim.x;

  // ================= P0: spiral permutation (analytic stable rank) =================
  for (int task = blockIdx.x; task < HWSZ / 128; task += nbk){
    const int j = task * 128 + tid;               // 0..16383
    const int y = j >> 7, x = j & 127;
    const int dy = y - 64, dx = x - 64;
    const int v = dy*dy + dx*dx;
    // strictly-smaller-d2 count: clipped circle, rows dy' in [-64,63], cols dx' in [-64,63]
    int cnt = 0;
    for (int yy = 0; yy < 128; ++yy){
      int dyy = yy - 64;
      int w = v - dyy*dyy;                        // need dx'^2 < w
      if (w > 0){
        int m = isqrt_floor(w - 1);               // largest |dx'| with dx'^2 < w
        int lo = m < 64 ? m : 64;
        int hi = m < 63 ? m : 63;
        cnt += lo + hi + 1;
      }
    }
    // same-bin (d2 == v), smaller flat index: rows above, plus same-row mirror
    {
      const int r = isqrt_floor(v);
      int yp0 = 64 - r; if (yp0 < 0) yp0 = 0;
      int yp1 = 64 + r + 1; if (yp1 > y) yp1 = y;
      for (int yp = yp0; yp < yp1; ++yp){
        int dyp = yp - 64;
        int tt = v - dyp*dyp;                     // >= 0 by construction
        int rr = isqrt_floor(tt);
        if (rr * rr == tt){
          cnt += (rr <= 64) ? 1 : 0;              // x = 64 - rr
          cnt += (rr >= 1 && rr <= 63) ? 1 : 0;   // x = 64 + rr, distinct
        }
      }
      if (x > 64) cnt += 1;                       // same-row mirror 128-x precedes
    }
    p.sp[cnt] = j;
  }
  grid.sync();

  // ================= P1: per-chunk pipeline + from-zero scan =================
  for (int task = blockIdx.x; task < NTASK; task += nbk){
    const int c = task & (NCH - 1), b = task >> 10;
    const int c0 = c * TCH;
    const float* Xb = p.X + (size_t)b * LTOT;
    float* s_pre = smem + O_PRE;
    float* s_dt  = smem + O_DT;
    float* s_dxm = smem + O_DXM;
    float* s_Bv  = smem + O_BV;
    float* s_Cv  = smem + O_CV;

    // step A: 12 gathers -> dwconv+silu -> u (cached) -> in_proj (xm half)
    if (tid < TCH + 3){
      const int m = tid;
      const int i = c0 - 3 + m;
      if (i < 0){
        #pragma unroll
        for (int d = 0; d < 8; ++d) s_pre[m*9 + d] = 0.f;
      } else {
        const int i2 = LTOT - 1 - i;
        const bool okm = (i > 0), okp = (i < LTOT - 1);
        int q[12];
        q[0]  = okm ? rho0(i - 1, p.sp) : 0;
        q[1]  =       rho0(i,     p.sp);
        q[2]  = okp ? rho0(i + 1, p.sp) : 0;
        q[3]  = okm ? rho1(i - 1, p.sp) : 0;
        q[4]  =       rho1(i,     p.sp);
        q[5]  = okp ? rho1(i + 1, p.sp) : 0;
        q[6]  = okm ? rho0(i2 + 1, p.sp) : 0;
        q[7]  =       rho0(i2,     p.sp);
        q[8]  = okp ? rho0(i2 - 1, p.sp) : 0;
        q[9]  = okm ? rho1(i2 + 1, p.sp) : 0;
        q[10] =       rho1(i2,     p.sp);
        q[11] = okp ? rho1(i2 - 1, p.sp) : 0;
        float xv[12];
        #pragma unroll
        for (int t = 0; t < 12; ++t) xv[t] = Xb[q[t]];
        if (!okm){ xv[0] = 0.f; xv[3] = 0.f; xv[6] = 0.f; xv[9]  = 0.f; }
        if (!okp){ xv[2] = 0.f; xv[5] = 0.f; xv[8] = 0.f; xv[11] = 0.f; }
        float u[4];
        #pragma unroll
        for (int k = 0; k < 4; ++k){
          float acc = p.dwb[k];
          acc = fmaf(p.dww[k*3+0], xv[k*3+0], acc);
          acc = fmaf(p.dww[k*3+1], xv[k*3+1], acc);
          acc = fmaf(p.dww[k*3+2], xv[k*3+2], acc);
          u[k] = siluf(acc);
        }
        p.ug4[(size_t)b * LTOT + i] = make_float4(u[0], u[1], u[2], u[3]);  // halo double-writes identical
        #pragma unroll
        for (int d = 0; d < 8; ++d){
          float acc =      p.ipw[d*4+0] * u[0];
          acc = fmaf(p.ipw[d*4+1], u[1], acc);
          acc = fmaf(p.ipw[d*4+2], u[2], acc);
          acc = fmaf(p.ipw[d*4+3], u[3], acc);
          s_pre[m*9 + d] = acc;
        }
      }
    }
    __syncthreads();

    // step B: causal conv4+silu -> xm ; x_proj -> dt, B, C ; store dt and dt*xm
    if (tid < TCH){
      const int t = tid;
      float xm[8];
      #pragma unroll
      for (int d = 0; d < 8; ++d){
        float acc = p.c1b[d];
        #pragma unroll
        for (int tau = 0; tau < 4; ++tau)
          acc = fmaf(p.c1w[d*4+tau], s_pre[(t+tau)*9 + d], acc);
        xm[d] = siluf(acc);
      }
      float dtr = p.xpw[0] * xm[0];
      #pragma unroll
      for (int d = 1; d < 8; ++d) dtr = fmaf(p.xpw[d], xm[d], dtr);
      #pragma unroll
      for (int s = 0; s < 16; ++s){
        float acc = p.xpw[(1+s)*8] * xm[0];
        #pragma unroll
        for (int d = 1; d < 8; ++d) acc = fmaf(p.xpw[(1+s)*8+d], xm[d], acc);
        s_Bv[s*SD + t] = acc;
        float acc2 = p.xpw[(17+s)*8] * xm[0];
        #pragma unroll
        for (int d = 1; d < 8; ++d) acc2 = fmaf(p.xpw[(17+s)*8+d], xm[d], acc2);
        s_Cv[s*SD + t] = acc2;
      }
      #pragma unroll
      for (int d = 0; d < 8; ++d){
        float dtv = softplusf(fmaf(p.dtpw[d], dtr, p.dtpb[d]));
        s_dt[d*SD + t]  = dtv;
        s_dxm[d*SD + t] = dtv * xm[d];
      }
    }
    __syncthreads();

    // step C: from-zero scan; emit y0 (s==0 lanes), chunk summary
    {
      const int d = tid >> 4, s = tid & 15;
      const float Ads = -__expf(p.Alog[tid]);   // tid == d*16+s
      float h = 0.f, sdt = 0.f;
      const float* pdt = s_dt + d*SD;
      const float* pdx = s_dxm + d*SD;
      const float* pB  = s_Bv + s*SD;
      const float* pC  = s_Cv + s*SD;
      float* yb = p.y0g + ((size_t)b * NCH + c) * 768 + d * 96;
      for (int t0 = 0; t0 < TCH; t0 += 4){
        const float4 dt4 = *reinterpret_cast<const float4*>(pdt + t0);
        const float4 dx4 = *reinterpret_cast<const float4*>(pdx + t0);
        const float4 B4  = *reinterpret_cast<const float4*>(pB + t0);
        const float4 C4  = *reinterpret_cast<const float4*>(pC + t0);
        sdt += dt4.x + dt4.y + dt4.z + dt4.w;
        float y0, y1, y2, y3;
        { float dA = __expf(dt4.x*Ads); h = fmaf(dA, h, dx4.x*B4.x); y0 = h*C4.x; }
        { float dA = __expf(dt4.y*Ads); h = fmaf(dA, h, dx4.y*B4.y); y1 = h*C4.y; }
        { float dA = __expf(dt4.z*Ads); h = fmaf(dA, h, dx4.z*B4.z); y2 = h*C4.z; }
        { float dA = __expf(dt4.w*Ads); h = fmaf(dA, h, dx4.w*B4.w); y3 = h*C4.w; }
        y0 = red16(y0); y1 = red16(y1); y2 = red16(y2); y3 = red16(y3);
        if (s == 0)
          *reinterpret_cast<float4*>(yb + t0) = make_float4(y0, y1, y2, y3);
      }
      const size_t base = ((size_t)b * NCH + c) * 128 + tid;
      p.chA[base] = __expf(Ads * sdt);          // product of dA over the chunk
      p.chB[base] = h;
    }
    __syncthreads();   // protect s_dt/s_Bv/s_Cv from next task's step B (step A only touches s_pre)
  }
  grid.sync();

  // ================= P2: combine level 1 (per-group prefixes) =================
  for (int task = blockIdx.x; task < NGRP * NB; task += nbk){
    const int g = task >> 2, b = task & 3;
    const size_t base = ((size_t)b * NCH + (size_t)g * GCH) * 128 + tid;
    float h = 0.f, a = 1.f;
    float A_[8], B_[8];
    #pragma unroll
    for (int m = 0; m < 8; ++m){ A_[m] = p.chA[base + (size_t)m*128]; B_[m] = p.chB[base + (size_t)m*128]; }
    for (int cc = 0; cc < GCH; cc += 8){
      float A2[8], B2[8];
      if (cc + 8 < GCH){
        #pragma unroll
        for (int m = 0; m < 8; ++m){ A2[m] = p.chA[base + (size_t)(cc+8+m)*128]; B2[m] = p.chB[base + (size_t)(cc+8+m)*128]; }
      } else {
        #pragma unroll
        for (int m = 0; m < 8; ++m){ A2[m] = 0.f; B2[m] = 0.f; }
      }
      #pragma unroll
      for (int m = 0; m < 8; ++m){
        p.hpre[base + (size_t)(cc+m)*128] = h;
        p.apre[base + (size_t)(cc+m)*128] = a;
        h = fmaf(A_[m], h, B_[m]);
        a *= A_[m];
      }
      #pragma unroll
      for (int m = 0; m < 8; ++m){ A_[m] = A2[m]; B_[m] = B2[m]; }
    }
    p.GA[(size_t)(g*4+b)*128 + tid] = a;
    p.GB[(size_t)(g*4+b)*128 + tid] = h;
  }
  grid.sync();

  // ================= P3: correction + epilogue (no serial chain, no gathers) =================
  for (int task = blockIdx.x; task < NTASK; task += nbk){
    const int c = task & (NCH - 1), b = task >> 10;
    const int c0 = c * TCH;
    const size_t cb = (size_t)b * NCH + c;
    float* s_yf = smem + O_PRE;       // also s_pre during stage 1-2
    float* s_sg = smem + C_SG;
    float* s_xm = smem + C_XM;
    float* s_Ct = smem + C_CT;
    float* s_zs = smem + C_ZS;
    float* s_hA = smem + C_HA;

    // stage 0: h_in assembly (inline group-boundary prefix) + per-(d,s) constants
    {
      const int g = c >> 6;
      const float hp = p.hpre[cb * 128 + tid];
      const float ap = p.apre[cb * 128 + tid];
      float Hv = 0.f;
      for (int gp = 0; gp < g; ++gp){
        const float ga = p.GA[(size_t)gp*512 + (size_t)b*128 + tid];
        const float gb = p.GB[(size_t)gp*512 + (size_t)b*128 + tid];
        Hv = fmaf(ga, Hv, gb);
      }
      s_hA[tid]       = fmaf(ap, Hv, hp);     // hin[d*16+s]
      s_hA[128 + tid] = -__expf(p.Alog[tid]); // Ads[d*16+s]
    }

    // stage 1: u-cache load -> in_proj (pre + z gate)
    if (tid < TCH + 3){
      const int m = tid;
      const int i = c0 - 3 + m;
      if (i < 0){
        #pragma unroll
        for (int d = 0; d < 8; ++d) s_yf[m*9 + d] = 0.f;
      } else {
        const float4 u4 = p.ug4[(size_t)b * LTOT + i];
        const float u[4] = {u4.x, u4.y, u4.z, u4.w};
        #pragma unroll
        for (int d = 0; d < 8; ++d){
          float acc =      p.ipw[d*4+0] * u[0];
          acc = fmaf(p.ipw[d*4+1], u[1], acc);
          acc = fmaf(p.ipw[d*4+2], u[2], acc);
          acc = fmaf(p.ipw[d*4+3], u[3], acc);
          s_yf[m*9 + d] = acc;                 // s_pre role
        }
        if (m >= 3){
          const int t0 = m - 3;
          #pragma unroll
          for (int d = 0; d < 8; ++d){
            float acc =      p.ipw[(8+d)*4+0] * u[0];
            acc = fmaf(p.ipw[(8+d)*4+1], u[1], acc);
            acc = fmaf(p.ipw[(8+d)*4+2], u[2], acc);
            acc = fmaf(p.ipw[(8+d)*4+3], u[3], acc);
            s_zs[d*96 + t0] = siluf(acc);
          }
        }
      }
    }
    __syncthreads();

    // stage 2: conv4+silu -> xm ; dt -> s_sg ; C -> s_Ct (t-major)
    if (tid < TCH){
      const int t = tid;
      float xm[8];
      #pragma unroll
      for (int d = 0; d < 8; ++d){
        float acc = p.c1b[d];
        #pragma unroll
        for (int tau = 0; tau < 4; ++tau)
          acc = fmaf(p.c1w[d*4+tau], s_yf[(t+tau)*9 + d], acc);
        float v = siluf(acc);
        xm[d] = v;
        s_xm[d*96 + t] = v;
      }
      float dtr = p.xpw[0] * xm[0];
      #pragma unroll
      for (int d = 1; d < 8; ++d) dtr = fmaf(p.xpw[d], xm[d], dtr);
      float* pct = s_Ct + t*20;
      #pragma unroll
      for (int s = 0; s < 16; ++s){
        float acc2 = p.xpw[(17+s)*8] * xm[0];
        #pragma unroll
        for (int d = 1; d < 8; ++d) acc2 = fmaf(p.xpw[(17+s)*8+d], xm[d], acc2);
        pct[s] = acc2;
      }
      #pragma unroll
      for (int d = 0; d < 8; ++d)
        s_sg[d*104 + t] = softplusf(fmaf(p.dtpw[d], dtr, p.dtpb[d]));
    }
    __syncthreads();

    // stage 3: in-place inclusive cumsum of dt -> sigma (8 serial lanes)
    if (tid < 8){
      float* ps = s_sg + tid*104;
      float run = 0.f;
      for (int t0 = 0; t0 < TCH; t0 += 4){
        const float4 d4 = *reinterpret_cast<const float4*>(ps + t0);
        float r0 = run + d4.x, r1 = r0 + d4.y, r2 = r1 + d4.z, r3 = r2 + d4.w;
        *reinterpret_cast<float4*>(ps + t0) = make_float4(r0, r1, r2, r3);
        run = r3;
      }
    }
    __syncthreads();

    // stage 4: correction, lanes = (d, tsub), in-register s-accumulation
    {
      const int d = tid >> 4, tsub = tid & 15;
      float w[16], A16[16];
      #pragma unroll
      for (int s = 0; s < 16; ++s){
        w[s]   = s_hA[d*16 + s];
        A16[s] = s_hA[128 + d*16 + s];
      }
      const float* py0 = p.y0g + cb * 768 + d * 96;
      for (int t = tsub; t < TCH; t += 16){
        const float sg = s_sg[d*104 + t];
        float acc = py0[t];
        const float* pc = s_Ct + t*20;
        #pragma unroll
        for (int s4 = 0; s4 < 16; s4 += 4){
          const float4 C4 = *reinterpret_cast<const float4*>(pc + s4);
          acc = fmaf(C4.x, __expf(A16[s4+0]*sg) * w[s4+0], acc);
          acc = fmaf(C4.y, __expf(A16[s4+1]*sg) * w[s4+1], acc);
          acc = fmaf(C4.z, __expf(A16[s4+2]*sg) * w[s4+2], acc);
          acc = fmaf(C4.w, __expf(A16[s4+3]*sg) * w[s4+3], acc);
        }
        s_yf[d*96 + t] = acc;
      }
    }
    __syncthreads();

    // stage 5: epilogue: skip + gate + out_proj + LN -> SoA planes
    if (tid < TCH){
      const int t = tid;
      const int i = c0 + t;
      float y[8];
      #pragma unroll
      for (int d = 0; d < 8; ++d)
        y[d] = (s_yf[d*96 + t] + s_xm[d*96 + t] * p.Dp[d]) * s_zs[d*96 + t];
      float o[4];
      #pragma unroll
      for (int e = 0; e < 4; ++e){
        float acc = p.opw[e*8] * y[0];
        #pragma unroll
        for (int d = 1; d < 8; ++d) acc = fmaf(p.opw[e*8+d], y[d], acc);
        o[e] = acc;
      }
      const float mu = 0.25f * (o[0] + o[1] + o[2] + o[3]);
      const float v0 = o[0] - mu, v1 = o[1] - mu, v2 = o[2] - mu, v3 = o[3] - mu;
      const float inv = rsqrtf(0.25f * (v0*v0 + v1*v1 + v2*v2 + v3*v3) + 1e-5f);
      const size_t base = (size_t)b * LTOT + i;
      p.outbuf[0*NBL + base] = fmaf(v0 * inv, p.lng[0], p.lnb[0]);
      p.outbuf[1*NBL + base] = fmaf(v1 * inv, p.lng[1], p.lnb[1]);
      p.outbuf[2*NBL + base] = fmaf(v2 * inv, p.lng[2], p.lnb[2]);
      p.outbuf[3*NBL + base] = fmaf(v3 * inv, p.lng[3], p.lnb[3]);
    }
    __syncthreads();   // s_yf/s_hA reused by next task's stages 0-1
  }
  grid.sync();

  // ================= P4: final gather + mean (SoA planes) =================
  for (int task = blockIdx.x; task < FTASK; task += nbk){
    const int idx = task * 128 + tid;     // 0..NBL-1
    const int b = idx / LTOT;
    const int l = idx - b * LTOT;
    const int q0 = rho0(l, p.sp), q1 = rho1(l, p.sp);
    const int j  = LTOT - 1 - l;
    const int q2 = rho0(j, p.sp), q3 = rho1(j, p.sp);
    const size_t pb = (size_t)b * LTOT;
    p.out[pb + l] = 0.25f * (p.outbuf[0*NBL + pb + q0] + p.outbuf[1*NBL + pb + q1] +
                             p.outbuf[2*NBL + pb + q2] + p.outbuf[3*NBL + pb + q3]);
  }
}

extern "C" void kernel_launch(void* const* d_in, const int* in_sizes, int n_in,
                              void* d_out, int out_size, void* d_ws, size_t ws_size,
                              hipStream_t stream) {
  // workspace layout (all rewritten every call):
  //   sp      16384 int                          (64 KB)
  //   chA/chB/hpre/apre  4 x 524288 f32          (8 MB)
  //   GA/GB              2 x 8192 f32
  //   ug      NB*LTOT float4                     (6.3 MB)
  //   y0g     NB*NCH*768 f32                     (12.6 MB)
  //   outbuf  4 planes x NB*LTOT f32 (SoA)       (6.3 MB)
  //   total ~ 33.4 MB
  int* wsI    = (int*)d_ws;
  int* sp     = wsI;
  float* chA  = (float*)(wsI + 16384);
  float* chB  = chA  + 524288;
  float* hpre = chB  + 524288;
  float* apre = hpre + 524288;
  float* GA   = apre + 524288;
  float* GB   = GA + 8192;
  float4* ug4 = (float4*)(GB + 8192);
  float* y0g  = (float*)(ug4) + (size_t)NB * LTOT * 4;
  float* outbuf = y0g + 3145728;

  Params prm;
  prm.X    = (const float*)d_in[0];
  prm.dww  = (const float*)d_in[1];
  prm.dwb  = (const float*)d_in[2];
  prm.ipw  = (const float*)d_in[3];
  prm.c1w  = (const float*)d_in[4];
  prm.c1b  = (const float*)d_in[5];
  prm.xpw  = (const float*)d_in[6];
  prm.dtpw = (const float*)d_in[7];
  prm.dtpb = (const float*)d_in[8];
  prm.Alog = (const float*)d_in[9];
  prm.Dp   = (const float*)d_in[10];
  prm.opw  = (const float*)d_in[11];
  prm.lng  = (const float*)d_in[12];
  prm.lnb  = (const float*)d_in[13];
  prm.sp = sp; prm.chA = chA; prm.chB = chB; prm.hpre = hpre; prm.apre = apre;
  prm.GA = GA; prm.GB = GB; prm.ug4 = ug4; prm.y0g = y0g; prm.outbuf = outbuf;
  prm.out = (float*)d_out;

  // grid = blocks/CU (occupancy-query, clamped for co-residency margin) x 256 CUs
  int maxb = 0;
  if (hipOccupancyMaxActiveBlocksPerMultiprocessor(&maxb, k_mega, 128, 0) != hipSuccess || maxb < 1)
    maxb = 6;
  if (maxb > 6) maxb = 6;
  dim3 grid(256 * maxb), block(128);
  void* args[] = { (void*)&prm };
  hipLaunchCooperativeKernel(k_mega, grid, block, args, 0u, stream);
}

// Round 7
// 196.979 us; speedup vs baseline: 3.4629x; 3.4629x over previous
//
#include <hip/hip_runtime.h>
#include <math.h>

// Problem constants: D_MODEL=4, D_INNER=8, D_STATE=16, D_CONV=4, DT_RANK=1
// x: (B=4, N=6, H=128, W=128) f32. L = 98304.
#define HWSZ  16384
#define LTOT  98304
#define NB    4
#define TCH   96           // chunk length
#define NCH   1024         // LTOT / TCH
#define SD    100          // k_scan t-stride: %4==0 (b128 align), d-offset 4 banks (2-way max = free)
#define NBL   (NB * LTOT)

// fast transcendentals: v_exp/v_log/v_rcp based; rel err ~1e-7, budget 2.7e-4
__device__ __forceinline__ float siluf(float x){
  return x * __builtin_amdgcn_rcpf(1.f + __expf(-x));
}
__device__ __forceinline__ float softplusf(float x){
  return fmaxf(x, 0.f) + __logf(1.f + __expf(-fabsf(x)));
}

// 16-lane (row-aligned) sum via DPP butterflies — pure VALU, no DS ops.
__device__ __forceinline__ float red16(float x){
  int v;
  v = __float_as_int(x);
  x += __int_as_float(__builtin_amdgcn_update_dpp(0, v, 0xB1, 0xF, 0xF, true));   // quad_perm xor1
  v = __float_as_int(x);
  x += __int_as_float(__builtin_amdgcn_update_dpp(0, v, 0x4E, 0xF, 0xF, true));   // quad_perm xor2
  v = __float_as_int(x);
  x += __int_as_float(__builtin_amdgcn_update_dpp(0, v, 0x141, 0xF, 0xF, true));  // row_half_mirror
  v = __float_as_int(x);
  x += __int_as_float(__builtin_amdgcn_update_dpp(0, v, 0x140, 0xF, 0xF, true));  // row_mirror
  return x;
}

// floor(sqrt(v)) exact for 0 <= v <= 2^24 via rn + one-step fixup
__device__ __forceinline__ int isqrt_floor(int v){
  int r = __float2int_rn(sqrtf((float)v));
  if (r * r > v) --r;
  else if ((r + 1) * (r + 1) <= v) ++r;
  return r;
}

// perm k=0 (scanA): i = n*HW + r -> spatial n*HW + sp[r]
__device__ __forceinline__ int rho0(int i, const int* __restrict__ sp){
  int n = i >> 14; int r = i & (HWSZ - 1);
  return (n << 14) + sp[r];
}
// perm k=1 (scanB): i = r*6 + n ; tid = (r even ? n : 5-n) -> tid*HW + sp[r]
__device__ __forceinline__ int rho1(int i, const int* __restrict__ sp){
  unsigned ui = (unsigned)i;
  unsigned r = ui / 6u; unsigned n = ui - r * 6u;
  unsigned t = (r & 1u) ? (5u - n) : n;
  return (int)((t << 14) + (unsigned)sp[r]);
}
// k=2 is rho0(L-1-i), k=3 is rho1(L-1-i)

// ---------------- perm build: analytic stable rank (no LDS, no serial prefix) ----------------
__global__ __launch_bounds__(128) void k_rank(int* __restrict__ sp){
  const int j = blockIdx.x * 128 + threadIdx.x;   // 0..16383
  const int y = j >> 7, x = j & 127;
  const int dy = y - 64, dx = x - 64;
  const int v = dy*dy + dx*dx;
  // strictly-smaller-d2 count: clipped circle, rows dy' in [-64,63], cols dx' in [-64,63]
  int cnt = 0;
  for (int yy = 0; yy < 128; ++yy){
    int dyy = yy - 64;
    int w = v - dyy*dyy;                          // need dx'^2 < w
    if (w > 0){
      int m = isqrt_floor(w - 1);                 // largest |dx'| with dx'^2 < w
      int lo = m < 64 ? m : 64;
      int hi = m < 63 ? m : 63;
      cnt += lo + hi + 1;
    }
  }
  // same-bin (d2 == v), smaller flat index: rows above, plus same-row mirror
  {
    const int r = isqrt_floor(v);
    int yp0 = 64 - r; if (yp0 < 0) yp0 = 0;
    int yp1 = 64 + r + 1; if (yp1 > y) yp1 = y;
    for (int yp = yp0; yp < yp1; ++yp){
      int dyp = yp - 64;
      int tt = v - dyp*dyp;                       // >= 0 by construction
      int rr = isqrt_floor(tt);
      if (rr * rr == tt){
        cnt += (rr <= 64) ? 1 : 0;                // x = 64 - rr
        cnt += (rr >= 1 && rr <= 63) ? 1 : 0;     // x = 64 + rr, distinct
      }
    }
    if (x > 64) cnt += 1;                         // same-row mirror 128-x precedes
  }
  sp[cnt] = j;
}

// ---------------- pass 1: per-chunk pipeline + from-zero scan ----------------
__global__ __launch_bounds__(128, 4)
void k_scan(const float* __restrict__ X,
            const float* __restrict__ dww, const float* __restrict__ dwb,
            const float* __restrict__ ipw,
            const float* __restrict__ c1w, const float* __restrict__ c1b,
            const float* __restrict__ xpw,
            const float* __restrict__ dtpw, const float* __restrict__ dtpb,
            const float* __restrict__ Alog,
            const int* __restrict__ sp,
            float* __restrict__ chA, float* __restrict__ chB,
            float* __restrict__ y0g, float4* __restrict__ ug4)
{
  const int c = blockIdx.x, b = blockIdx.y;
  const int c0 = c * TCH;
  const int tid = threadIdx.x;
  const float* Xb = X + (size_t)b * LTOT;

  __shared__ __align__(16) float s_pre[(TCH + 3) * 9];
  __shared__ __align__(16) float s_dt[8 * SD];
  __shared__ __align__(16) float s_dxm[8 * SD];     // dt * xm (s-independent product)
  __shared__ __align__(16) float s_Bv[16 * SD];
  __shared__ __align__(16) float s_Cv[16 * SD];

  // ---- step A: 12 gathers -> dwconv+silu -> u (cached) -> in_proj (xm half)
  if (tid < TCH + 3){
    const int m = tid;
    const int i = c0 - 3 + m;
    if (i < 0){
      #pragma unroll
      for (int d = 0; d < 8; ++d) s_pre[m*9 + d] = 0.f;
    } else {
      const int i2 = LTOT - 1 - i;
      const bool okm = (i > 0), okp = (i < LTOT - 1);
      int q[12];
      q[0]  = okm ? rho0(i - 1, sp) : 0;
      q[1]  =       rho0(i,     sp);
      q[2]  = okp ? rho0(i + 1, sp) : 0;
      q[3]  = okm ? rho1(i - 1, sp) : 0;
      q[4]  =       rho1(i,     sp);
      q[5]  = okp ? rho1(i + 1, sp) : 0;
      q[6]  = okm ? rho0(i2 + 1, sp) : 0;
      q[7]  =       rho0(i2,     sp);
      q[8]  = okp ? rho0(i2 - 1, sp) : 0;
      q[9]  = okm ? rho1(i2 + 1, sp) : 0;
      q[10] =       rho1(i2,     sp);
      q[11] = okp ? rho1(i2 - 1, sp) : 0;
      float xv[12];
      #pragma unroll
      for (int t = 0; t < 12; ++t) xv[t] = Xb[q[t]];
      if (!okm){ xv[0] = 0.f; xv[3] = 0.f; xv[6] = 0.f; xv[9]  = 0.f; }
      if (!okp){ xv[2] = 0.f; xv[5] = 0.f; xv[8] = 0.f; xv[11] = 0.f; }
      float u[4];
      #pragma unroll
      for (int k = 0; k < 4; ++k){
        float acc = dwb[k];
        acc = fmaf(dww[k*3+0], xv[k*3+0], acc);
        acc = fmaf(dww[k*3+1], xv[k*3+1], acc);
        acc = fmaf(dww[k*3+2], xv[k*3+2], acc);
        u[k] = siluf(acc);
      }
      ug4[(size_t)b * LTOT + i] = make_float4(u[0], u[1], u[2], u[3]);  // halo double-writes identical
      #pragma unroll
      for (int d = 0; d < 8; ++d){
        float acc =      ipw[d*4+0] * u[0];
        acc = fmaf(ipw[d*4+1], u[1], acc);
        acc = fmaf(ipw[d*4+2], u[2], acc);
        acc = fmaf(ipw[d*4+3], u[3], acc);
        s_pre[m*9 + d] = acc;
      }
    }
  }
  __syncthreads();

  // ---- step B: causal conv4+silu -> xm ; x_proj -> dt, B, C ; store dt and dt*xm
  if (tid < TCH){
    const int t = tid;
    float xm[8];
    #pragma unroll
    for (int d = 0; d < 8; ++d){
      float acc = c1b[d];
      #pragma unroll
      for (int tau = 0; tau < 4; ++tau)
        acc = fmaf(c1w[d*4+tau], s_pre[(t+tau)*9 + d], acc);
      xm[d] = siluf(acc);
    }
    float dtr = xpw[0] * xm[0];
    #pragma unroll
    for (int d = 1; d < 8; ++d) dtr = fmaf(xpw[d], xm[d], dtr);
    #pragma unroll
    for (int s = 0; s < 16; ++s){
      float acc = xpw[(1+s)*8] * xm[0];
      #pragma unroll
      for (int d = 1; d < 8; ++d) acc = fmaf(xpw[(1+s)*8+d], xm[d], acc);
      s_Bv[s*SD + t] = acc;
      float acc2 = xpw[(17+s)*8] * xm[0];
      #pragma unroll
      for (int d = 1; d < 8; ++d) acc2 = fmaf(xpw[(17+s)*8+d], xm[d], acc2);
      s_Cv[s*SD + t] = acc2;
    }
    #pragma unroll
    for (int d = 0; d < 8; ++d){
      float dtv = softplusf(fmaf(dtpw[d], dtr, dtpb[d]));
      s_dt[d*SD + t]  = dtv;
      s_dxm[d*SD + t] = dtv * xm[d];
    }
  }
  __syncthreads();

  // ---- step C: from-zero scan; emit y0 (s==0 lanes), chunk summary
  {
    const int d = tid >> 4, s = tid & 15;
    const float Ads = -__expf(Alog[tid]);   // tid == d*16+s
    float h = 0.f, sdt = 0.f;
    const float* pdt = s_dt + d*SD;
    const float* pdx = s_dxm + d*SD;
    const float* pB  = s_Bv + s*SD;
    const float* pC  = s_Cv + s*SD;
    float* yb = y0g + ((size_t)b * NCH + c) * 768 + d * 96;
    for (int t0 = 0; t0 < TCH; t0 += 4){
      const float4 dt4 = *reinterpret_cast<const float4*>(pdt + t0);
      const float4 dx4 = *reinterpret_cast<const float4*>(pdx + t0);
      const float4 B4  = *reinterpret_cast<const float4*>(pB + t0);
      const float4 C4  = *reinterpret_cast<const float4*>(pC + t0);
      sdt += dt4.x + dt4.y + dt4.z + dt4.w;
      float y0, y1, y2, y3;
      { float dA = __expf(dt4.x*Ads); h = fmaf(dA, h, dx4.x*B4.x); y0 = h*C4.x; }
      { float dA = __expf(dt4.y*Ads); h = fmaf(dA, h, dx4.y*B4.y); y1 = h*C4.y; }
      { float dA = __expf(dt4.z*Ads); h = fmaf(dA, h, dx4.z*B4.z); y2 = h*C4.z; }
      { float dA = __expf(dt4.w*Ads); h = fmaf(dA, h, dx4.w*B4.w); y3 = h*C4.w; }
      y0 = red16(y0); y1 = red16(y1); y2 = red16(y2); y3 = red16(y3);
      if (s == 0)
        *reinterpret_cast<float4*>(yb + t0) = make_float4(y0, y1, y2, y3);
    }
    const size_t base = ((size_t)b * NCH + c) * 128 + tid;
    chA[base] = __expf(Ads * sdt);          // product of dA over the chunk
    chB[base] = h;
  }
}

// ---------------- combine: wave-parallel scan over chunks -> full h_in per chunk ------------
// One wave per (b, idx) chain; 1024 chunks = 16 segments of 64 lanes; 6-step shfl scan + carry.
// op order: applying elem j then elem i: (a,h) = (a_i*a_j, a_i*h_j + h_i)
__global__ __launch_bounds__(128) void k_comb(const float* __restrict__ chA,
                                              const float* __restrict__ chB,
                                              float* __restrict__ hin){
  const int wave = (blockIdx.x << 1) | (threadIdx.x >> 6);  // 0..511 chain id
  const int lane = threadIdx.x & 63;
  const int b   = wave >> 7;
  const int idx = wave & 127;
  const size_t basebi = (size_t)b * NCH * 128 + idx;
  float carry = 0.f;
  float a = chA[basebi + (size_t)lane * 128];
  float h = chB[basebi + (size_t)lane * 128];
  for (int seg = 0; seg < NCH / 64; ++seg){
    float aN = 1.f, hN = 0.f;
    if (seg + 1 < NCH / 64){
      const size_t off = basebi + (size_t)((seg + 1) * 64 + lane) * 128;
      aN = chA[off]; hN = chB[off];
    }
    #pragma unroll
    for (int o = 1; o < 64; o <<= 1){
      float aj = __shfl_up(a, o, 64);
      float hj = __shfl_up(h, o, 64);
      if (lane >= o){ h = fmaf(a, hj, h); a *= aj; }
    }
    // exclusive prefix for this lane's chunk, then apply carry
    float ae = __shfl_up(a, 1, 64);
    float he = __shfl_up(h, 1, 64);
    if (lane == 0){ ae = 1.f; he = 0.f; }
    hin[basebi + (size_t)(seg * 64 + lane) * 128] = fmaf(ae, carry, he);
    // carry update from lane 63's inclusive combo
    float aL = __shfl(a, 63, 64);
    float hL = __shfl(h, 63, 64);
    carry = fmaf(aL, carry, hL);
    a = aN; h = hN;
  }
}

// ---------------- pass 2: correction + epilogue (no serial chain, no gathers) ----------------
__global__ __launch_bounds__(128, 4)
void k_corr(const float4* __restrict__ ug4,
            const float* __restrict__ ipw,
            const float* __restrict__ c1w, const float* __restrict__ c1b,
            const float* __restrict__ xpw,
            const float* __restrict__ dtpw, const float* __restrict__ dtpb,
            const float* __restrict__ Alog, const float* __restrict__ Dp,
            const float* __restrict__ opw,
            const float* __restrict__ lng, const float* __restrict__ lnb,
            const float* __restrict__ hin,
            const float* __restrict__ y0g,
            float* __restrict__ outbuf)   // SoA: [e][b][i]
{
  const int c = blockIdx.x, b = blockIdx.y;
  const int c0 = c * TCH;
  const int tid = threadIdx.x;
  const size_t cb = (size_t)b * NCH + c;

  __shared__ __align__(16) float s_pre[(TCH + 3) * 9];  // 891 f; reused as s_yf (768 f, stride 96)
  __shared__ __align__(16) float s_sg[8 * 104];         // dt then in-place cumsum -> sigma
  __shared__ __align__(16) float s_xm[8 * 96];
  __shared__ __align__(16) float s_Ct[96 * 20];         // C transposed: [t][s], stride 20 (2-way banks, b128-aligned)
  __shared__ __align__(16) float s_zs[8 * 96];
  __shared__ __align__(16) float s_hA[256];             // [0:128) hin, [128:256) Ads
  float* s_yf = s_pre;

  // ---- stage 0: per-(d,s) constants to LDS (hin precomputed by k_comb)
  s_hA[tid]       = hin[cb * 128 + tid];
  s_hA[128 + tid] = -__expf(Alog[tid]);

  // ---- stage 1: u-cache load -> in_proj (pre + z gate)
  if (tid < TCH + 3){
    const int m = tid;
    const int i = c0 - 3 + m;
    if (i < 0){
      #pragma unroll
      for (int d = 0; d < 8; ++d) s_pre[m*9 + d] = 0.f;
    } else {
      const float4 u4 = ug4[(size_t)b * LTOT + i];
      const float u[4] = {u4.x, u4.y, u4.z, u4.w};
      #pragma unroll
      for (int d = 0; d < 8; ++d){
        float acc =      ipw[d*4+0] * u[0];
        acc = fmaf(ipw[d*4+1], u[1], acc);
        acc = fmaf(ipw[d*4+2], u[2], acc);
        acc = fmaf(ipw[d*4+3], u[3], acc);
        s_pre[m*9 + d] = acc;
      }
      if (m >= 3){
        const int t0 = m - 3;
        #pragma unroll
        for (int d = 0; d < 8; ++d){
          float acc =      ipw[(8+d)*4+0] * u[0];
          acc = fmaf(ipw[(8+d)*4+1], u[1], acc);
          acc = fmaf(ipw[(8+d)*4+2], u[2], acc);
          acc = fmaf(ipw[(8+d)*4+3], u[3], acc);
          s_zs[d*96 + t0] = siluf(acc);
        }
      }
    }
  }
  __syncthreads();

  // ---- stage 2: conv4+silu -> xm ; dt -> s_sg ; C -> s_Ct (t-major)
  if (tid < TCH){
    const int t = tid;
    float xm[8];
    #pragma unroll
    for (int d = 0; d < 8; ++d){
      float acc = c1b[d];
      #pragma unroll
      for (int tau = 0; tau < 4; ++tau)
        acc = fmaf(c1w[d*4+tau], s_pre[(t+tau)*9 + d], acc);
      float v = siluf(acc);
      xm[d] = v;
      s_xm[d*96 + t] = v;
    }
    float dtr = xpw[0] * xm[0];
    #pragma unroll
    for (int d = 1; d < 8; ++d) dtr = fmaf(xpw[d], xm[d], dtr);
    float* pct = s_Ct + t*20;
    #pragma unroll
    for (int s = 0; s < 16; ++s){
      float acc2 = xpw[(17+s)*8] * xm[0];
      #pragma unroll
      for (int d = 1; d < 8; ++d) acc2 = fmaf(xpw[(17+s)*8+d], xm[d], acc2);
      pct[s] = acc2;
    }
    #pragma unroll
    for (int d = 0; d < 8; ++d)
      s_sg[d*104 + t] = softplusf(fmaf(dtpw[d], dtr, dtpb[d]));
  }
  __syncthreads();

  // ---- stage 3: in-place inclusive cumsum of dt -> sigma (8 serial lanes)
  if (tid < 8){
    float* ps = s_sg + tid*104;
    float run = 0.f;
    for (int t0 = 0; t0 < TCH; t0 += 4){
      const float4 d4 = *reinterpret_cast<const float4*>(ps + t0);
      float r0 = run + d4.x, r1 = r0 + d4.y, r2 = r1 + d4.z, r3 = r2 + d4.w;
      *reinterpret_cast<float4*>(ps + t0) = make_float4(r0, r1, r2, r3);
      run = r3;
    }
  }
  __syncthreads();

  // ---- stage 4: correction, lanes = (d, tsub), in-register s-accumulation
  {
    const int d = tid >> 4, tsub = tid & 15;
    float w[16], A16[16];
    #pragma unroll
    for (int s = 0; s < 16; ++s){
      w[s]   = s_hA[d*16 + s];
      A16[s] = s_hA[128 + d*16 + s];
    }
    const float* py0 = y0g + cb * 768 + d * 96;
    for (int t = tsub; t < TCH; t += 16){
      const float sg = s_sg[d*104 + t];
      float acc = py0[t];
      const float* pc = s_Ct + t*20;
      #pragma unroll
      for (int s4 = 0; s4 < 16; s4 += 4){
        const float4 C4 = *reinterpret_cast<const float4*>(pc + s4);
        acc = fmaf(C4.x, __expf(A16[s4+0]*sg) * w[s4+0], acc);
        acc = fmaf(C4.y, __expf(A16[s4+1]*sg) * w[s4+1], acc);
        acc = fmaf(C4.z, __expf(A16[s4+2]*sg) * w[s4+2], acc);
        acc = fmaf(C4.w, __expf(A16[s4+3]*sg) * w[s4+3], acc);
      }
      s_yf[d*96 + t] = acc;
    }
  }
  __syncthreads();

  // ---- stage 5: epilogue: skip + gate + out_proj + LN -> SoA planes
  if (tid < TCH){
    const int t = tid;
    const int i = c0 + t;
    float y[8];
    #pragma unroll
    for (int d = 0; d < 8; ++d)
      y[d] = (s_yf[d*96 + t] + s_xm[d*96 + t] * Dp[d]) * s_zs[d*96 + t];
    float o[4];
    #pragma unroll
    for (int e = 0; e < 4; ++e){
      float acc = opw[e*8] * y[0];
      #pragma unroll
      for (int d = 1; d < 8; ++d) acc = fmaf(opw[e*8+d], y[d], acc);
      o[e] = acc;
    }
    const float mu = 0.25f * (o[0] + o[1] + o[2] + o[3]);
    const float v0 = o[0] - mu, v1 = o[1] - mu, v2 = o[2] - mu, v3 = o[3] - mu;
    const float inv = rsqrtf(0.25f * (v0*v0 + v1*v1 + v2*v2 + v3*v3) + 1e-5f);
    const size_t base = (size_t)b * LTOT + i;
    outbuf[0*NBL + base] = fmaf(v0 * inv, lng[0], lnb[0]);
    outbuf[1*NBL + base] = fmaf(v1 * inv, lng[1], lnb[1]);
    outbuf[2*NBL + base] = fmaf(v2 * inv, lng[2], lnb[2]);
    outbuf[3*NBL + base] = fmaf(v3 * inv, lng[3], lnb[3]);
  }
}

// ---------------- final gather + mean (SoA planes) ----------------
__global__ __launch_bounds__(256) void k_final(const float* __restrict__ outbuf,
                                               const int* __restrict__ sp,
                                               float* __restrict__ out){
  const int l = blockIdx.x * 256 + threadIdx.x;   // spatial flat index 0..L-1
  const int b = blockIdx.y;
  const int q0 = rho0(l, sp), q1 = rho1(l, sp);
  const int j  = LTOT - 1 - l;
  const int q2 = rho0(j, sp), q3 = rho1(j, sp);
  const size_t pb = (size_t)b * LTOT;
  out[pb + l] = 0.25f * (outbuf[0*NBL + pb + q0] + outbuf[1*NBL + pb + q1] +
                         outbuf[2*NBL + pb + q2] + outbuf[3*NBL + pb + q3]);
}

extern "C" void kernel_launch(void* const* d_in, const int* in_sizes, int n_in,
                              void* d_out, int out_size, void* d_ws, size_t ws_size,
                              hipStream_t stream) {
  const float* X    = (const float*)d_in[0];   // (4,6,128,128)
  const float* dww  = (const float*)d_in[1];   // (4,1,3)
  const float* dwb  = (const float*)d_in[2];   // (4)
  const float* ipw  = (const float*)d_in[3];   // (16,4)
  const float* c1w  = (const float*)d_in[4];   // (8,1,4)
  const float* c1b  = (const float*)d_in[5];   // (8)
  const float* xpw  = (const float*)d_in[6];   // (33,8)
  const float* dtpw = (const float*)d_in[7];   // (8,1)
  const float* dtpb = (const float*)d_in[8];   // (8)
  const float* Alog = (const float*)d_in[9];   // (8,16)
  const float* Dp   = (const float*)d_in[10];  // (8)
  const float* opw  = (const float*)d_in[11];  // (4,8)
  const float* lng  = (const float*)d_in[12];  // (4)
  const float* lnb  = (const float*)d_in[13];  // (4)
  float* out = (float*)d_out;

  // workspace layout (all rewritten every call):
  //   sp      16384 int                          (64 KB)
  //   chA/chB/hin  3 x 524288 f32                (6 MB)
  //   ug      NB*LTOT float4                     (6.3 MB)
  //   y0g     NB*NCH*768 f32                     (12.6 MB)
  //   outbuf  4 planes x NB*LTOT f32 (SoA)       (6.3 MB)
  //   total ~ 31.3 MB
  int* wsI    = (int*)d_ws;
  int* sp     = wsI;
  float* chA  = (float*)(wsI + 16384);
  float* chB  = chA + 524288;
  float* hin  = chB + 524288;
  float4* ug4 = (float4*)(hin + 524288);
  float* y0g  = (float*)(ug4) + (size_t)NB * LTOT * 4;
  float* outbuf = y0g + 3145728;

  k_rank<<<128, 128, 0, stream>>>(sp);
  k_scan<<<dim3(NCH, NB), 128, 0, stream>>>(X, dww, dwb, ipw, c1w, c1b, xpw,
      dtpw, dtpb, Alog, sp, chA, chB, y0g, ug4);
  k_comb<<<256, 128, 0, stream>>>(chA, chB, hin);
  k_corr<<<dim3(NCH, NB), 128, 0, stream>>>(ug4, ipw, c1w, c1b, xpw,
      dtpw, dtpb, Alog, Dp, opw, lng, lnb, hin, y0g, outbuf);
  k_final<<<dim3(LTOT / 256, NB), 256, 0, stream>>>(outbuf, sp, out);
}

// Round 8
// 192.419 us; speedup vs baseline: 3.5450x; 1.0237x over previous
//
#include <hip/hip_runtime.h>
#include <math.h>

// Problem constants: D_MODEL=4, D_INNER=8, D_STATE=16, D_CONV=4, DT_RANK=1
// x: (B=4, N=6, H=128, W=128) f32. L = 98304.
#define HWSZ  16384
#define LTOT  98304
#define NB    4
#define TCH   96           // chunk length
#define NCH   1024         // LTOT / TCH
#define SD    100          // k_scan t-stride: %4==0 (b128 align), d-offset 4 banks (2-way max = free)
#define NBL   (NB * LTOT)

// fast transcendentals: v_exp/v_log/v_rcp based; rel err ~1e-7, budget 2.7e-4
__device__ __forceinline__ float siluf(float x){
  return x * __builtin_amdgcn_rcpf(1.f + __expf(-x));
}
__device__ __forceinline__ float softplusf(float x){
  return fmaxf(x, 0.f) + __logf(1.f + __expf(-fabsf(x)));
}

// 16-lane (row-aligned) sum via DPP butterflies — pure VALU, no DS ops.
__device__ __forceinline__ float red16(float x){
  int v;
  v = __float_as_int(x);
  x += __int_as_float(__builtin_amdgcn_update_dpp(0, v, 0xB1, 0xF, 0xF, true));   // quad_perm xor1
  v = __float_as_int(x);
  x += __int_as_float(__builtin_amdgcn_update_dpp(0, v, 0x4E, 0xF, 0xF, true));   // quad_perm xor2
  v = __float_as_int(x);
  x += __int_as_float(__builtin_amdgcn_update_dpp(0, v, 0x141, 0xF, 0xF, true));  // row_half_mirror
  v = __float_as_int(x);
  x += __int_as_float(__builtin_amdgcn_update_dpp(0, v, 0x140, 0xF, 0xF, true));  // row_mirror
  return x;
}

// floor(sqrt(v)) exact for 0 <= v <= 2^24 via rn + one-step fixup
__device__ __forceinline__ int isqrt_floor(int v){
  int r = __float2int_rn(sqrtf((float)v));
  if (r * r > v) --r;
  else if ((r + 1) * (r + 1) <= v) ++r;
  return r;
}

// perm k=0 (scanA): i = n*HW + r -> spatial n*HW + sp[r]
__device__ __forceinline__ int rho0(int i, const int* __restrict__ sp){
  int n = i >> 14; int r = i & (HWSZ - 1);
  return (n << 14) + sp[r];
}
// perm k=1 (scanB): i = r*6 + n ; tid = (r even ? n : 5-n) -> tid*HW + sp[r]
__device__ __forceinline__ int rho1(int i, const int* __restrict__ sp){
  unsigned ui = (unsigned)i;
  unsigned r = ui / 6u; unsigned n = ui - r * 6u;
  unsigned t = (r & 1u) ? (5u - n) : n;
  return (int)((t << 14) + (unsigned)sp[r]);
}
// k=2 is rho0(L-1-i), k=3 is rho1(L-1-i)

// ---------------- perm build: analytic stable rank (no LDS, no serial prefix) ----------------
__global__ __launch_bounds__(128) void k_rank(int* __restrict__ sp){
  const int j = blockIdx.x * 128 + threadIdx.x;   // 0..16383
  const int y = j >> 7, x = j & 127;
  const int dy = y - 64, dx = x - 64;
  const int v = dy*dy + dx*dx;
  // strictly-smaller-d2 count: clipped circle, rows dy' in [-64,63], cols dx' in [-64,63]
  int cnt = 0;
  for (int yy = 0; yy < 128; ++yy){
    int dyy = yy - 64;
    int w = v - dyy*dyy;                          // need dx'^2 < w
    if (w > 0){
      int m = isqrt_floor(w - 1);                 // largest |dx'| with dx'^2 < w
      int lo = m < 64 ? m : 64;
      int hi = m < 63 ? m : 63;
      cnt += lo + hi + 1;
    }
  }
  // same-bin (d2 == v), smaller flat index: rows above, plus same-row mirror
  {
    const int r = isqrt_floor(v);
    int yp0 = 64 - r; if (yp0 < 0) yp0 = 0;
    int yp1 = 64 + r + 1; if (yp1 > y) yp1 = y;
    for (int yp = yp0; yp < yp1; ++yp){
      int dyp = yp - 64;
      int tt = v - dyp*dyp;                       // >= 0 by construction
      int rr = isqrt_floor(tt);
      if (rr * rr == tt){
        cnt += (rr <= 64) ? 1 : 0;                // x = 64 - rr
        cnt += (rr >= 1 && rr <= 63) ? 1 : 0;     // x = 64 + rr, distinct
      }
    }
    if (x > 64) cnt += 1;                         // same-row mirror 128-x precedes
  }
  sp[cnt] = j;
}

// ---------------- pass 1: per-chunk pipeline + from-zero scan; caches xm/zs/C/sigma ---------
__global__ __launch_bounds__(128, 4)
void k_scan(const float* __restrict__ X,
            const float* __restrict__ dww, const float* __restrict__ dwb,
            const float* __restrict__ ipw,
            const float* __restrict__ c1w, const float* __restrict__ c1b,
            const float* __restrict__ xpw,
            const float* __restrict__ dtpw, const float* __restrict__ dtpb,
            const float* __restrict__ Alog,
            const int* __restrict__ sp,
            float* __restrict__ chA, float* __restrict__ chB,
            float* __restrict__ y0g,
            float* __restrict__ Cg,  float* __restrict__ xmg,
            float* __restrict__ zsg, float* __restrict__ sgg)
{
  const int c = blockIdx.x, b = blockIdx.y;
  const int c0 = c * TCH;
  const int tid = threadIdx.x;
  const float* Xb = X + (size_t)b * LTOT;
  const size_t cb = (size_t)b * NCH + c;

  __shared__ __align__(16) float s_pre[(TCH + 3) * 9];
  __shared__ __align__(16) float s_dt[8 * SD];
  __shared__ __align__(16) float s_dxm[8 * SD];     // dt * xm (s-independent product)
  __shared__ __align__(16) float s_Bv[16 * SD];
  __shared__ __align__(16) float s_Cv[16 * SD];

  // ---- step A: 12 gathers -> dwconv+silu -> in_proj (xm pre + z gate); cache zs
  if (tid < TCH + 3){
    const int m = tid;
    const int i = c0 - 3 + m;
    if (i < 0){
      #pragma unroll
      for (int d = 0; d < 8; ++d) s_pre[m*9 + d] = 0.f;
    } else {
      const int i2 = LTOT - 1 - i;
      const bool okm = (i > 0), okp = (i < LTOT - 1);
      int q[12];
      q[0]  = okm ? rho0(i - 1, sp) : 0;
      q[1]  =       rho0(i,     sp);
      q[2]  = okp ? rho0(i + 1, sp) : 0;
      q[3]  = okm ? rho1(i - 1, sp) : 0;
      q[4]  =       rho1(i,     sp);
      q[5]  = okp ? rho1(i + 1, sp) : 0;
      q[6]  = okm ? rho0(i2 + 1, sp) : 0;
      q[7]  =       rho0(i2,     sp);
      q[8]  = okp ? rho0(i2 - 1, sp) : 0;
      q[9]  = okm ? rho1(i2 + 1, sp) : 0;
      q[10] =       rho1(i2,     sp);
      q[11] = okp ? rho1(i2 - 1, sp) : 0;
      float xv[12];
      #pragma unroll
      for (int t = 0; t < 12; ++t) xv[t] = Xb[q[t]];
      if (!okm){ xv[0] = 0.f; xv[3] = 0.f; xv[6] = 0.f; xv[9]  = 0.f; }
      if (!okp){ xv[2] = 0.f; xv[5] = 0.f; xv[8] = 0.f; xv[11] = 0.f; }
      float u[4];
      #pragma unroll
      for (int k = 0; k < 4; ++k){
        float acc = dwb[k];
        acc = fmaf(dww[k*3+0], xv[k*3+0], acc);
        acc = fmaf(dww[k*3+1], xv[k*3+1], acc);
        acc = fmaf(dww[k*3+2], xv[k*3+2], acc);
        u[k] = siluf(acc);
      }
      #pragma unroll
      for (int d = 0; d < 8; ++d){
        float acc =      ipw[d*4+0] * u[0];
        acc = fmaf(ipw[d*4+1], u[1], acc);
        acc = fmaf(ipw[d*4+2], u[2], acc);
        acc = fmaf(ipw[d*4+3], u[3], acc);
        s_pre[m*9 + d] = acc;
      }
      if (m >= 3){                                  // z gate -> global cache
        const int t0 = m - 3;
        float zs8[8];
        #pragma unroll
        for (int d = 0; d < 8; ++d){
          float acc =      ipw[(8+d)*4+0] * u[0];
          acc = fmaf(ipw[(8+d)*4+1], u[1], acc);
          acc = fmaf(ipw[(8+d)*4+2], u[2], acc);
          acc = fmaf(ipw[(8+d)*4+3], u[3], acc);
          zs8[d] = siluf(acc);
        }
        float* pz = zsg + (cb*96 + t0)*8;
        *reinterpret_cast<float4*>(pz)     = make_float4(zs8[0], zs8[1], zs8[2], zs8[3]);
        *reinterpret_cast<float4*>(pz + 4) = make_float4(zs8[4], zs8[5], zs8[6], zs8[7]);
      }
    }
  }
  __syncthreads();

  // ---- step B: conv4+silu -> xm (cached) ; x_proj -> dt, B, C (C cached)
  if (tid < TCH){
    const int t = tid;
    float xm[8];
    #pragma unroll
    for (int d = 0; d < 8; ++d){
      float acc = c1b[d];
      #pragma unroll
      for (int tau = 0; tau < 4; ++tau)
        acc = fmaf(c1w[d*4+tau], s_pre[(t+tau)*9 + d], acc);
      xm[d] = siluf(acc);
    }
    {
      float* px = xmg + (cb*96 + t)*8;
      *reinterpret_cast<float4*>(px)     = make_float4(xm[0], xm[1], xm[2], xm[3]);
      *reinterpret_cast<float4*>(px + 4) = make_float4(xm[4], xm[5], xm[6], xm[7]);
    }
    float dtr = xpw[0] * xm[0];
    #pragma unroll
    for (int d = 1; d < 8; ++d) dtr = fmaf(xpw[d], xm[d], dtr);
    float C16[16];
    #pragma unroll
    for (int s = 0; s < 16; ++s){
      float acc = xpw[(1+s)*8] * xm[0];
      #pragma unroll
      for (int d = 1; d < 8; ++d) acc = fmaf(xpw[(1+s)*8+d], xm[d], acc);
      s_Bv[s*SD + t] = acc;
      float acc2 = xpw[(17+s)*8] * xm[0];
      #pragma unroll
      for (int d = 1; d < 8; ++d) acc2 = fmaf(xpw[(17+s)*8+d], xm[d], acc2);
      s_Cv[s*SD + t] = acc2;
      C16[s] = acc2;
    }
    {
      float* pc = Cg + (cb*96 + t)*16;
      #pragma unroll
      for (int s4 = 0; s4 < 16; s4 += 4)
        *reinterpret_cast<float4*>(pc + s4) = make_float4(C16[s4], C16[s4+1], C16[s4+2], C16[s4+3]);
    }
    #pragma unroll
    for (int d = 0; d < 8; ++d){
      float dtv = softplusf(fmaf(dtpw[d], dtr, dtpb[d]));
      s_dt[d*SD + t]  = dtv;
      s_dxm[d*SD + t] = dtv * xm[d];
    }
  }
  __syncthreads();

  // ---- step C: from-zero scan; emit y0 + sigma (s==0 lanes), chunk summary
  {
    const int d = tid >> 4, s = tid & 15;
    const float Ads = -__expf(Alog[tid]);   // tid == d*16+s
    float h = 0.f, sdt = 0.f;
    const float* pdt = s_dt + d*SD;
    const float* pdx = s_dxm + d*SD;
    const float* pB  = s_Bv + s*SD;
    const float* pC  = s_Cv + s*SD;
    float* yb = y0g + cb * 768 + d * 96;
    float* sb = sgg + (cb*8 + d) * 96;
    for (int t0 = 0; t0 < TCH; t0 += 4){
      const float4 dt4 = *reinterpret_cast<const float4*>(pdt + t0);
      const float4 dx4 = *reinterpret_cast<const float4*>(pdx + t0);
      const float4 B4  = *reinterpret_cast<const float4*>(pB + t0);
      const float4 C4  = *reinterpret_cast<const float4*>(pC + t0);
      // running inclusive cumsum (same serial order as the old stage-3 pass)
      float r0 = sdt + dt4.x, r1 = r0 + dt4.y, r2 = r1 + dt4.z, r3 = r2 + dt4.w;
      sdt = r3;
      float y0, y1, y2, y3;
      { float dA = __expf(dt4.x*Ads); h = fmaf(dA, h, dx4.x*B4.x); y0 = h*C4.x; }
      { float dA = __expf(dt4.y*Ads); h = fmaf(dA, h, dx4.y*B4.y); y1 = h*C4.y; }
      { float dA = __expf(dt4.z*Ads); h = fmaf(dA, h, dx4.z*B4.z); y2 = h*C4.z; }
      { float dA = __expf(dt4.w*Ads); h = fmaf(dA, h, dx4.w*B4.w); y3 = h*C4.w; }
      y0 = red16(y0); y1 = red16(y1); y2 = red16(y2); y3 = red16(y3);
      if (s == 0){
        *reinterpret_cast<float4*>(yb + t0) = make_float4(y0, y1, y2, y3);
        *reinterpret_cast<float4*>(sb + t0) = make_float4(r0, r1, r2, r3);
      }
    }
    const size_t base = cb * 128 + tid;
    chA[base] = __expf(Ads * sdt);          // product of dA over the chunk
    chB[base] = h;
  }
}

// ---------------- combine: wave-parallel scan over chunks -> full h_in per chunk ------------
// One wave per (b, idx) chain; 1024 chunks = 16 segments of 64 lanes; 6-step shfl scan + carry.
__global__ __launch_bounds__(128) void k_comb(const float* __restrict__ chA,
                                              const float* __restrict__ chB,
                                              float* __restrict__ hin){
  const int wave = (blockIdx.x << 1) | (threadIdx.x >> 6);  // 0..511 chain id
  const int lane = threadIdx.x & 63;
  const int b   = wave >> 7;
  const int idx = wave & 127;
  const size_t basebi = (size_t)b * NCH * 128 + idx;
  float carry = 0.f;
  float a = chA[basebi + (size_t)lane * 128];
  float h = chB[basebi + (size_t)lane * 128];
  for (int seg = 0; seg < NCH / 64; ++seg){
    float aN = 1.f, hN = 0.f;
    if (seg + 1 < NCH / 64){
      const size_t off = basebi + (size_t)((seg + 1) * 64 + lane) * 128;
      aN = chA[off]; hN = chB[off];
    }
    #pragma unroll
    for (int o = 1; o < 64; o <<= 1){
      float aj = __shfl_up(a, o, 64);
      float hj = __shfl_up(h, o, 64);
      if (lane >= o){ h = fmaf(a, hj, h); a *= aj; }
    }
    float ae = __shfl_up(a, 1, 64);
    float he = __shfl_up(h, 1, 64);
    if (lane == 0){ ae = 1.f; he = 0.f; }
    hin[basebi + (size_t)(seg * 64 + lane) * 128] = fmaf(ae, carry, he);
    float aL = __shfl(a, 63, 64);
    float hL = __shfl(h, 63, 64);
    carry = fmaf(aL, carry, hL);
    a = aN; h = hN;
  }
}

// ---------------- pass 2: correction + epilogue — pure consumer, no recompute --------------
__global__ __launch_bounds__(128)
void k_corr(const float* __restrict__ Cg,  const float* __restrict__ sgg,
            const float* __restrict__ xmg, const float* __restrict__ zsg,
            const float* __restrict__ Alog, const float* __restrict__ Dp,
            const float* __restrict__ opw,
            const float* __restrict__ lng, const float* __restrict__ lnb,
            const float* __restrict__ hin,
            const float* __restrict__ y0g,
            float* __restrict__ outbuf)   // SoA: [e][b][i]
{
  const int c = blockIdx.x, b = blockIdx.y;
  const int c0 = c * TCH;
  const int tid = threadIdx.x;
  const size_t cb = (size_t)b * NCH + c;

  __shared__ float s_hA[256];             // [0:128) hin, [128:256) Ads
  __shared__ float s_yf[8 * 96];          // [d*96 + t]

  // stage 0: constants (same-wave produce/consume: each wave reads only lanes it wrote)
  s_hA[tid]       = hin[cb * 128 + tid];
  s_hA[128 + tid] = -__expf(Alog[tid]);

  // stage 1: correction, lanes = (d, tsub), everything streamed from global (L2)
  {
    const int d = tid >> 4, tsub = tid & 15;
    float w[16], A16[16];
    #pragma unroll
    for (int s = 0; s < 16; ++s){
      w[s]   = s_hA[d*16 + s];
      A16[s] = s_hA[128 + d*16 + s];
    }
    const float* psg = sgg + (cb*8 + d) * 96;
    const float* py0 = y0g + cb * 768 + d * 96;
    const float* pC  = Cg + cb * 96 * 16;
    #pragma unroll
    for (int t = tsub; t < TCH; t += 16){
      const float sg = psg[t];
      float acc = py0[t];
      const float* pc = pC + t*16;
      #pragma unroll
      for (int s4 = 0; s4 < 16; s4 += 4){
        const float4 C4 = *reinterpret_cast<const float4*>(pc + s4);
        acc = fmaf(C4.x, __expf(A16[s4+0]*sg) * w[s4+0], acc);
        acc = fmaf(C4.y, __expf(A16[s4+1]*sg) * w[s4+1], acc);
        acc = fmaf(C4.z, __expf(A16[s4+2]*sg) * w[s4+2], acc);
        acc = fmaf(C4.w, __expf(A16[s4+3]*sg) * w[s4+3], acc);
      }
      s_yf[d*96 + t] = acc;
    }
  }
  __syncthreads();

  // stage 2: epilogue: skip + gate + out_proj + LN -> SoA planes
  if (tid < TCH){
    const int t = tid;
    const int i = c0 + t;
    const float* px = xmg + (cb*96 + t)*8;
    const float* pz = zsg + (cb*96 + t)*8;
    const float4 xa = *reinterpret_cast<const float4*>(px);
    const float4 xbv = *reinterpret_cast<const float4*>(px + 4);
    const float4 za = *reinterpret_cast<const float4*>(pz);
    const float4 zb = *reinterpret_cast<const float4*>(pz + 4);
    const float xm8[8] = {xa.x, xa.y, xa.z, xa.w, xbv.x, xbv.y, xbv.z, xbv.w};
    const float zs8[8] = {za.x, za.y, za.z, za.w, zb.x, zb.y, zb.z, zb.w};
    float y[8];
    #pragma unroll
    for (int d = 0; d < 8; ++d)
      y[d] = (s_yf[d*96 + t] + xm8[d] * Dp[d]) * zs8[d];
    float o[4];
    #pragma unroll
    for (int e = 0; e < 4; ++e){
      float acc = opw[e*8] * y[0];
      #pragma unroll
      for (int d = 1; d < 8; ++d) acc = fmaf(opw[e*8+d], y[d], acc);
      o[e] = acc;
    }
    const float mu = 0.25f * (o[0] + o[1] + o[2] + o[3]);
    const float v0 = o[0] - mu, v1 = o[1] - mu, v2 = o[2] - mu, v3 = o[3] - mu;
    const float inv = rsqrtf(0.25f * (v0*v0 + v1*v1 + v2*v2 + v3*v3) + 1e-5f);
    const size_t base = (size_t)b * LTOT + i;
    outbuf[0*NBL + base] = fmaf(v0 * inv, lng[0], lnb[0]);
    outbuf[1*NBL + base] = fmaf(v1 * inv, lng[1], lnb[1]);
    outbuf[2*NBL + base] = fmaf(v2 * inv, lng[2], lnb[2]);
    outbuf[3*NBL + base] = fmaf(v3 * inv, lng[3], lnb[3]);
  }
}

// ---------------- final gather + mean (SoA planes) ----------------
__global__ __launch_bounds__(256) void k_final(const float* __restrict__ outbuf,
                                               const int* __restrict__ sp,
                                               float* __restrict__ out){
  const int l = blockIdx.x * 256 + threadIdx.x;   // spatial flat index 0..L-1
  const int b = blockIdx.y;
  const int q0 = rho0(l, sp), q1 = rho1(l, sp);
  const int j  = LTOT - 1 - l;
  const int q2 = rho0(j, sp), q3 = rho1(j, sp);
  const size_t pb = (size_t)b * LTOT;
  out[pb + l] = 0.25f * (outbuf[0*NBL + pb + q0] + outbuf[1*NBL + pb + q1] +
                         outbuf[2*NBL + pb + q2] + outbuf[3*NBL + pb + q3]);
}

extern "C" void kernel_launch(void* const* d_in, const int* in_sizes, int n_in,
                              void* d_out, int out_size, void* d_ws, size_t ws_size,
                              hipStream_t stream) {
  const float* X    = (const float*)d_in[0];   // (4,6,128,128)
  const float* dww  = (const float*)d_in[1];   // (4,1,3)
  const float* dwb  = (const float*)d_in[2];   // (4)
  const float* ipw  = (const float*)d_in[3];   // (16,4)
  const float* c1w  = (const float*)d_in[4];   // (8,1,4)
  const float* c1b  = (const float*)d_in[5];   // (8)
  const float* xpw  = (const float*)d_in[6];   // (33,8)
  const float* dtpw = (const float*)d_in[7];   // (8,1)
  const float* dtpb = (const float*)d_in[8];   // (8)
  const float* Alog = (const float*)d_in[9];   // (8,16)
  const float* Dp   = (const float*)d_in[10];  // (8)
  const float* opw  = (const float*)d_in[11];  // (4,8)
  const float* lng  = (const float*)d_in[12];  // (4)
  const float* lnb  = (const float*)d_in[13];  // (4)
  float* out = (float*)d_out;

  // workspace layout (all rewritten every call), ~88.2 MB total:
  //   sp 16384 int | chA/chB/hin 3x524288 | y0g 3145728 | Cg 6291456
  //   xmg/zsg/sgg 3x3145728 | outbuf 1572864   (floats)
  int* wsI    = (int*)d_ws;
  int* sp     = wsI;
  float* chA  = (float*)(wsI + 16384);
  float* chB  = chA + 524288;
  float* hin  = chB + 524288;
  float* y0g  = hin + 524288;
  float* Cg   = y0g + 3145728;
  float* xmg  = Cg  + 6291456;
  float* zsg  = xmg + 3145728;
  float* sgg  = zsg + 3145728;
  float* outbuf = sgg + 3145728;

  k_rank<<<128, 128, 0, stream>>>(sp);
  k_scan<<<dim3(NCH, NB), 128, 0, stream>>>(X, dww, dwb, ipw, c1w, c1b, xpw,
      dtpw, dtpb, Alog, sp, chA, chB, y0g, Cg, xmg, zsg, sgg);
  k_comb<<<256, 128, 0, stream>>>(chA, chB, hin);
  k_corr<<<dim3(NCH, NB), 128, 0, stream>>>(Cg, sgg, xmg, zsg,
      Alog, Dp, opw, lng, lnb, hin, y0g, outbuf);
  k_final<<<dim3(LTOT / 256, NB), 256, 0, stream>>>(outbuf, sp, out);
}